// Round 10
// baseline (416.509 us; speedup 1.0000x reference)
//
#include <hip/hip_runtime.h>
#include <math.h>

#define SDIM   256
#define HID    512
#define NH     5
#define HEADS  10
#define POP    4096
#define ITERS  4
#define ELITE  819
#define INIT_STDF 0.4f
#define MIN_STDF  0.1f

// ws layout:
//   floats: base1[10][512] @0, q_part[2][10][4096] @5120, state @87040 (7 f)
//   bytes WS_W2S_BYTE+: W2S split/transposed weights, slab layout:
//   [h][cb(2)][jc(16)] slabs of 16384 ushorts: {hi[kg4][col256][ji8], lo[...]}
#define WS_BASE1 0
#define WS_Q     5120
#define WS_STATE 87040
#define WS_W2S_BYTE 348224
#define W2S_USHORTS (HEADS * 2 * 16 * 16384)
#define WS_NEED_BYTES (WS_W2S_BYTE + (size_t)W2S_USHORTS * 2)

typedef __attribute__((ext_vector_type(4))) float f32x4;
typedef __attribute__((ext_vector_type(16))) float f32x16;
typedef __attribute__((ext_vector_type(8))) short bf16x8;

static __device__ __forceinline__ unsigned short bf16_rne(float x) {
    unsigned b = __float_as_uint(x);
    return (unsigned short)((b + 0x7FFFu + ((b >> 16) & 1u)) >> 16);
}

// packed f32x2 -> bf16x2 (hardware cvt_pk, RNE)
static __device__ __forceinline__ unsigned pack2(float x, float y) {
    unsigned r;
    asm("v_cvt_pk_bf16_f32 %0, %1, %2" : "=v"(r) : "v"(x), "v"(y));
    return r;
}

static __device__ __forceinline__ float clip1(float x) {
    return fminf(fmaxf(x, -1.f), 1.f);
}

// ---------------------------------------------------------------------------
// Kernel 1: base1[h][j] = b1[h][j] + sum_i s[i] * W1[h][i][j]; init state
// ---------------------------------------------------------------------------
__global__ __launch_bounds__(256) void k_base(const float* __restrict__ state,
                                              const float* __restrict__ W1,
                                              const float* __restrict__ b1,
                                              float* __restrict__ ws)
{
    const int h = blockIdx.y;
    const int j = blockIdx.x * 256 + threadIdx.x;
    const float* w1h = W1 + (size_t)h * 258 * HID;
    float acc = b1[h * HID + j];
    for (int i = 0; i < SDIM; ++i)
        acc += state[i] * w1h[(size_t)i * HID + j];
    ws[WS_BASE1 + h * HID + j] = acc;

    if (h == 0 && blockIdx.x == 0 && threadIdx.x == 0) {
        float* st = ws + WS_STATE;
        st[0] = 0.f; st[1] = 0.f;
        st[2] = INIT_STDF; st[3] = INIT_STDF;
        st[4] = 0.f; st[5] = 0.f;
        st[6] = -3.402823466e38f;
    }
}

// ---------------------------------------------------------------------------
// Kernel 1b: W2 -> W2S (transpose + RNE hi/lo split). Coalesced both sides.
// ---------------------------------------------------------------------------
__global__ __launch_bounds__(256) void k_split(const float* __restrict__ W2,
                                               unsigned short* __restrict__ W2S)
{
    const int h = blockIdx.z, cb = blockIdx.y, jc = blockIdx.x;
    const int c = threadIdx.x;
    unsigned short* slab = W2S + (size_t)((h * 2 + cb) * 16 + jc) * 16384;
    #pragma unroll
    for (int jg = 0; jg < 4; ++jg) {
        unsigned hp[4], lp[4];
        #pragma unroll
        for (int i = 0; i < 4; ++i) {
            const int j = jc * 32 + jg * 8 + 2 * i;
            float v0 = W2[(size_t)(h * HID + j) * HID + cb * 256 + c];
            float v1 = W2[(size_t)(h * HID + j + 1) * HID + cb * 256 + c];
            unsigned short h0 = bf16_rne(v0), h1 = bf16_rne(v1);
            float f0 = __uint_as_float((unsigned)h0 << 16);
            float f1 = __uint_as_float((unsigned)h1 << 16);
            unsigned short l0 = bf16_rne(v0 - f0), l1 = bf16_rne(v1 - f1);
            hp[i] = (unsigned)h0 | ((unsigned)h1 << 16);
            lp[i] = (unsigned)l0 | ((unsigned)l1 << 16);
        }
        uint4 HV, LV;
        HV.x = hp[0]; HV.y = hp[1]; HV.z = hp[2]; HV.w = hp[3];
        LV.x = lp[0]; LV.y = lp[1]; LV.z = lp[2]; LV.w = lp[3];
        *(uint4*)&slab[jg * 2048 + c * 8] = HV;
        *(uint4*)&slab[8192 + jg * 2048 + c * 8] = LV;
    }
}

// ---------------------------------------------------------------------------
// Kernel 2: same occupancy-first structure as R9 (512 thr / 8 waves,
// 64 rows x 256 cols, A via LDS dbuf, B direct global->VGPR, one barrier
// per chunk) but inner MFMA switched to 32x32x16: per wave two 32x32 tiles,
// acc = 2 x f32x16 = 32 AGPR (unchanged occupancy), 12 MFMA/chunk at the
// higher 32x32 rate (2382 vs 2075 TF) and half the instruction count.
// Fragment maps: A row=lane&31, k=(lane>>5)*8+i; B col=lane&31, same k;
// C/D (m74/m101): col=lane&31, row=(reg&3)+8*(reg>>2)+4*(lane>>5).
// ---------------------------------------------------------------------------
__global__ __launch_bounds__(512, 4) void k_score_mfma8(
    const float* __restrict__ noise, const float* __restrict__ W1,
    const unsigned short* __restrict__ W2S,
    const float* __restrict__ b2, const float* __restrict__ W3,
    float* __restrict__ ws, int t)
{
    __shared__ unsigned short As[2][4096];   // dbuf: {hi[kg4][row64][ji8], lo}
    __shared__ float red[8][64];

    const int tid = threadIdx.x;
    const int bid = blockIdx.x;
    // bijective XCD remap (1280 = 8*160): consecutive w share (h,cb) panel
    const int w = (bid & 7) * 160 + (bid >> 3);
    const int h = w >> 7;
    const int rem = w & 127;
    const int cb = rem >> 6;
    const int rs = rem & 63;            // row-stripe of 64

    const int lane = tid & 63;
    const int wv = tid >> 6;            // 0..7 -> 32-col strip
    const int l31 = lane & 31;
    const int lg = lane >> 5;           // k-subgroup 0/1

    // computeA role (threads 0..255): row = tid&63, kg = (tid>>6)&3
    const int arow = tid & 63;
    const int akg = (tid >> 6) & 3;

    const float* st = ws + WS_STATE;
    const float mu0 = st[0], mu1 = st[1], sd0 = st[2], sd1 = st[3];
    float2 e = *(const float2*)&noise[((size_t)t * POP + rs * 64 + arow) * 2];
    const float a0 = clip1(mu0 + sd0 * e.x);
    const float a1 = clip1(mu1 + sd1 * e.y);

    const float* base1 = ws + WS_BASE1 + h * HID;
    const float* w1u = W1 + ((size_t)h * 258 + 256) * HID;
    const float* w1v = W1 + ((size_t)h * 258 + 257) * HID;
    const unsigned short* bslab = W2S + (size_t)((h * 2 + cb) * 16) * 16384;
    // B frag base: kg = ks*2 + lg, col = wv*32 + l31 -> +ks*4096; lo +8192
    const int bco = lg * 2048 + (wv * 32 + l31) * 8;
    // A frag base: kg = ks*2 + lg, row = mi*32 + l31 -> +ks*1024 + mi*256
    const int ar0 = lg * 512 + l31 * 8;

    // compute A chunk jc (rank-2 + relu + cvt_pk hi/lo split) into As[buf]
    auto computeA = [&](int jc, int buf) {
        if (tid < 256) {
            const int j = jc * 32 + akg * 8;
            f32x4 b0 = *(const f32x4*)&base1[j];
            f32x4 b1v = *(const f32x4*)&base1[j + 4];
            f32x4 u0 = *(const f32x4*)&w1u[j];
            f32x4 u1 = *(const f32x4*)&w1u[j + 4];
            f32x4 v0 = *(const f32x4*)&w1v[j];
            f32x4 v1 = *(const f32x4*)&w1v[j + 4];
            float hv[8];
            #pragma unroll
            for (int i = 0; i < 4; ++i) {
                hv[i]     = fmaxf(b0[i] + a0 * u0[i] + a1 * v0[i], 0.f);
                hv[4 + i] = fmaxf(b1v[i] + a0 * u1[i] + a1 * v1[i], 0.f);
            }
            unsigned ph[4], pl[4];
            #pragma unroll
            for (int i = 0; i < 4; ++i) {
                ph[i] = pack2(hv[2 * i], hv[2 * i + 1]);
                float fx = __uint_as_float(ph[i] << 16);
                float fy = __uint_as_float(ph[i] & 0xFFFF0000u);
                pl[i] = pack2(hv[2 * i] - fx, hv[2 * i + 1] - fy);
            }
            uint4 HV, LV;
            HV.x = ph[0]; HV.y = ph[1]; HV.z = ph[2]; HV.w = ph[3];
            LV.x = pl[0]; LV.y = pl[1]; LV.z = pl[2]; LV.w = pl[3];
            *(uint4*)&As[buf][akg * 512 + arow * 8] = HV;
            *(uint4*)&As[buf][2048 + akg * 512 + arow * 8] = LV;
        }
    };

    f32x16 acc[2];
    #pragma unroll
    for (int mi = 0; mi < 2; ++mi)
        #pragma unroll
        for (int i = 0; i < 16; ++i) acc[mi][i] = 0.f;

    // prologue: A(0) into buf 0; B(0) into regs
    computeA(0, 0);
    bf16x8 BH[2], BL[2];
    #pragma unroll
    for (int ks = 0; ks < 2; ++ks) {
        BH[ks] = *(const bf16x8*)(bslab + bco + ks * 4096);
        BL[ks] = *(const bf16x8*)(bslab + 8192 + bco + ks * 4096);
    }
    __syncthreads();

    int cur = 0;
    #pragma unroll 1
    for (int kc = 0; kc < 16; ++kc) {
        // A fragments from shared tile (8 x ds_read_b128, contiguous)
        bf16x8 AH[2][2], AL[2][2];   // [ks][mi]
        #pragma unroll
        for (int ks = 0; ks < 2; ++ks)
            #pragma unroll
            for (int mi = 0; mi < 2; ++mi) {
                const int ad = ar0 + ks * 1024 + mi * 256;
                AH[ks][mi] = *(const bf16x8*)&As[cur][ad];
                AL[ks][mi] = *(const bf16x8*)&As[cur][2048 + ad];
            }
        // prefetch next-chunk B (clamped; hidden under this chunk's MFMAs)
        const int nc = (kc < 15) ? kc + 1 : 15;
        const unsigned short* bnc = bslab + (size_t)nc * 16384;
        bf16x8 nBH[2], nBL[2];
        #pragma unroll
        for (int ks = 0; ks < 2; ++ks) {
            nBH[ks] = *(const bf16x8*)(bnc + bco + ks * 4096);
            nBL[ks] = *(const bf16x8*)(bnc + 8192 + bco + ks * 4096);
        }
        // 3 passes x 4 independent 32x32x16 MFMAs
        __builtin_amdgcn_s_setprio(1);
        #pragma unroll
        for (int ks = 0; ks < 2; ++ks)
            #pragma unroll
            for (int mi = 0; mi < 2; ++mi)
                acc[mi] = __builtin_amdgcn_mfma_f32_32x32x16_bf16(
                    AH[ks][mi], BH[ks], acc[mi], 0, 0, 0);
        #pragma unroll
        for (int ks = 0; ks < 2; ++ks)
            #pragma unroll
            for (int mi = 0; mi < 2; ++mi)
                acc[mi] = __builtin_amdgcn_mfma_f32_32x32x16_bf16(
                    AL[ks][mi], BH[ks], acc[mi], 0, 0, 0);
        #pragma unroll
        for (int ks = 0; ks < 2; ++ks)
            #pragma unroll
            for (int mi = 0; mi < 2; ++mi)
                acc[mi] = __builtin_amdgcn_mfma_f32_32x32x16_bf16(
                    AH[ks][mi], BL[ks], acc[mi], 0, 0, 0);
        __builtin_amdgcn_s_setprio(0);
        // next A tile into the other buffer, then one barrier
        computeA(nc, cur ^ 1);
        __syncthreads();
        #pragma unroll
        for (int ks = 0; ks < 2; ++ks) { BH[ks] = nBH[ks]; BL[ks] = nBL[ks]; }
        cur ^= 1;
    }

    // epilogue: q_part = sum over this block's 256 cols of
    //           relu(acc + b2[col]) * W3[col]
    // C/D 32x32 layout: col = l31, row = (reg&3) + 8*(reg>>2) + 4*lg
    const int gcol = cb * 256 + wv * 32 + l31;
    const float b2v = b2[h * HID + gcol];
    const float w3v = W3[h * HID + gcol];
    #pragma unroll
    for (int mi = 0; mi < 2; ++mi)
        #pragma unroll
        for (int r = 0; r < 16; ++r) {
            float v = fmaxf(acc[mi][r] + b2v, 0.f) * w3v;
            v += __shfl_xor(v, 1);
            v += __shfl_xor(v, 2);
            v += __shfl_xor(v, 4);
            v += __shfl_xor(v, 8);
            v += __shfl_xor(v, 16);
            if (l31 == 0)
                red[wv][mi * 32 + (r & 3) + 8 * (r >> 2) + 4 * lg] = v;
        }
    __syncthreads();
    if (tid < 64) {
        float q = 0.f;
        #pragma unroll
        for (int s = 0; s < 8; ++s) q += red[s][tid];
        ws[WS_Q + (size_t)(cb * HEADS + h) * POP + rs * 64 + tid] = q;
    }
}

// ---------------------------------------------------------------------------
// Kernel 2 (fp32 fallback, used only if ws too small): writes part0, zeroes
// part1 so k_select's partial-sum read stays correct.
// ---------------------------------------------------------------------------
__global__ __launch_bounds__(256) void k_score(const float* __restrict__ noise,
                                               const float* __restrict__ W1,
                                               const float* __restrict__ W2,
                                               const float* __restrict__ b2,
                                               const float* __restrict__ W3,
                                               float* __restrict__ ws, int t)
{
    __shared__ float h1[32][HID];
    __shared__ float a0s[32], a1s[32];
    __shared__ float red[2][16][2];

    const int tid = threadIdx.x;
    const int h   = blockIdx.y;
    const int p0  = blockIdx.x * 32;

    if (tid < 32) {
        const float* st = ws + WS_STATE;
        const int p = p0 + tid;
        float e0 = noise[((size_t)t * POP + p) * 2 + 0];
        float e1 = noise[((size_t)t * POP + p) * 2 + 1];
        a0s[tid] = fminf(fmaxf(st[0] + st[2] * e0, -1.f), 1.f);
        a1s[tid] = fminf(fmaxf(st[1] + st[3] * e1, -1.f), 1.f);
    }
    __syncthreads();

    const float* base1 = ws + WS_BASE1 + h * HID;
    const float* w1u = W1 + ((size_t)h * 258 + 256) * HID;
    const float* w1v = W1 + ((size_t)h * 258 + 257) * HID;
    #pragma unroll
    for (int jj = 0; jj < 2; ++jj) {
        int j = tid + jj * 256;
        float bb = base1[j], uu = w1u[j], vv = w1v[j];
        #pragma unroll
        for (int p = 0; p < 32; ++p)
            h1[p][j] = fmaxf(bb + a0s[p] * uu + a1s[p] * vv, 0.f);
    }
    __syncthreads();

    const int pg = tid >> 7;
    const int kl = tid & 127;
    const float* W2h = W2 + (size_t)h * HID * HID + kl;

    float acc[16][4];
    #pragma unroll
    for (int p = 0; p < 16; ++p)
        #pragma unroll
        for (int dk = 0; dk < 4; ++dk) acc[p][dk] = 0.f;

    for (int j0 = 0; j0 < HID; j0 += 4) {
        float w[4][4];
        #pragma unroll
        for (int dj = 0; dj < 4; ++dj)
            #pragma unroll
            for (int dk = 0; dk < 4; ++dk)
                w[dj][dk] = W2h[(size_t)(j0 + dj) * HID + dk * 128];
        #pragma unroll
        for (int p = 0; p < 16; ++p) {
            const float4 hv = *(const float4*)&h1[pg * 16 + p][j0];
            #pragma unroll
            for (int dk = 0; dk < 4; ++dk)
                acc[p][dk] += hv.x * w[0][dk] + hv.y * w[1][dk]
                            + hv.z * w[2][dk] + hv.w * w[3][dk];
        }
    }

    float b2v[4], w3v[4];
    #pragma unroll
    for (int dk = 0; dk < 4; ++dk) {
        b2v[dk] = b2[h * HID + kl + dk * 128];
        w3v[dk] = W3[h * HID + kl + dk * 128];
    }
    const int wid  = tid >> 6;
    const int lane = tid & 63;
    const int wig  = wid & 1;
    #pragma unroll
    for (int p = 0; p < 16; ++p) {
        float v = 0.f;
        #pragma unroll
        for (int dk = 0; dk < 4; ++dk)
            v += fmaxf(acc[p][dk] + b2v[dk], 0.f) * w3v[dk];
        #pragma unroll
        for (int off = 32; off; off >>= 1) v += __shfl_down(v, off);
        if (lane == 0) red[pg][p][wig] = v;
    }
    __syncthreads();
    if (tid < 32) {
        int pp = tid & 15, g = tid >> 4;
        ws[WS_Q + (size_t)h * POP + p0 + g * 16 + pp] =
            red[g][pp][0] + red[g][pp][1];
        ws[WS_Q + (size_t)(HEADS + h) * POP + p0 + g * 16 + pp] = 0.f;
    }
}

// ---------------------------------------------------------------------------
// Kernel 3 (1024 threads): scores from q partials (+b3), exact top-819
// radix select, elite mean/std (ddof=1, double accum), best_a update.
// ---------------------------------------------------------------------------
__global__ __launch_bounds__(1024) void k_select(const float* __restrict__ noise,
                                                 const float* __restrict__ b3,
                                                 float* __restrict__ ws,
                                                 float* __restrict__ out, int t)
{
    __shared__ float    sc[POP];        // 16 KB
    __shared__ unsigned uk[POP];        // 16 KB
    __shared__ unsigned hist[256];
    __shared__ int      scan2[1024];
    __shared__ float    rf[1024];
    __shared__ int      ri_[1024];
    __shared__ double   rd[1024];
    __shared__ unsigned s_prefix;
    __shared__ int      s_r;

    const int tid = threadIdx.x;
    const float* q = ws + WS_Q;
    float* st = ws + WS_STATE;
    const float mu0 = st[0], mu1 = st[1], sd0 = st[2], sd1 = st[3];

    // scores = mean_h min(q1,q2); q[h] = part0 + part1 + b3[h]
    {
        const int p = tid * 4;
        f32x4 s = (f32x4){0.f, 0.f, 0.f, 0.f};
        #pragma unroll
        for (int hh = 0; hh < NH; ++hh) {
            f32x4 qa0 = *(const f32x4*)&q[(size_t)hh * POP + p];
            f32x4 qa1 = *(const f32x4*)&q[(size_t)(HEADS + hh) * POP + p];
            f32x4 qb0 = *(const f32x4*)&q[(size_t)(NH + hh) * POP + p];
            f32x4 qb1 = *(const f32x4*)&q[(size_t)(HEADS + NH + hh) * POP + p];
            float ba = b3[hh], bb = b3[NH + hh];
            #pragma unroll
            for (int i = 0; i < 4; ++i)
                s[i] += fminf(qa0[i] + qa1[i] + ba, qb0[i] + qb1[i] + bb);
        }
        #pragma unroll
        for (int i = 0; i < 4; ++i) {
            float v = s[i] * 0.2f;
            sc[p + i] = v;
            unsigned b = __float_as_uint(v);
            uk[p + i] = (b & 0x80000000u) ? ~b : (b | 0x80000000u);
        }
    }
    __syncthreads();

    // max + argmax (lowest index on ties); threads own disjoint ascending
    // index ranges so strict '>' keeps the lowest index within a thread.
    float mv = -3.402823466e38f; int mi = 0;
    #pragma unroll
    for (int k = 0; k < 4; ++k) {
        const int p = tid * 4 + k;
        float v = sc[p];
        if (v > mv) { mv = v; mi = p; }
    }
    rf[tid] = mv; ri_[tid] = mi;
    __syncthreads();
    for (int off = 512; off; off >>= 1) {
        if (tid < off) {
            float ov = rf[tid + off]; int oi = ri_[tid + off];
            if (ov > rf[tid] || (ov == rf[tid] && oi < ri_[tid])) {
                rf[tid] = ov; ri_[tid] = oi;
            }
        }
        __syncthreads();
    }
    const float maxsc = rf[0];
    const int argmax = ri_[0];
    __syncthreads();

    // radix select with parallel suffix-scan digit pick
    unsigned prefix = 0; int r = ELITE;
    for (int shift = 24; shift >= 0; shift -= 8) {
        if (tid < 256) hist[tid] = 0;
        __syncthreads();
        const unsigned himask = (shift < 24) ? (0xFFFFFFFFu << (shift + 8)) : 0u;
        for (int p = tid; p < POP; p += 1024) {
            unsigned key = uk[p];
            if ((key & himask) == prefix)
                atomicAdd(&hist[(key >> shift) & 255u], 1u);
        }
        __syncthreads();
        scan2[tid] = (tid < 256) ? (int)hist[tid] : 0;
        __syncthreads();
        for (int off = 1; off < 256; off <<= 1) {
            int v = (tid < 256 && tid + off < 256) ? scan2[tid + off] : 0;
            __syncthreads();
            if (tid < 256) scan2[tid] += v;
            __syncthreads();
        }
        if (tid < 256) {
            int above = (tid < 255) ? scan2[tid + 1] : 0;
            if (scan2[tid] >= r && above < r) {
                s_prefix = prefix | ((unsigned)tid << shift);
                s_r = r - above;
            }
        }
        __syncthreads();
        prefix = s_prefix; r = s_r;
        __syncthreads();
    }
    const unsigned uT = prefix;
    const int take = r;

    // tie ranks (index order) via prefix scan over contiguous 4-chunks
    int tieloc = 0;
    {
        const int base = tid * 4;
        #pragma unroll
        for (int k = 0; k < 4; ++k) if (uk[base + k] == uT) tieloc++;
    }
    scan2[tid] = tieloc;
    __syncthreads();
    for (int off = 1; off < 1024; off <<= 1) {
        int v = (tid >= off) ? scan2[tid - off] : 0;
        __syncthreads();
        scan2[tid] += v;
        __syncthreads();
    }
    const int tieExcl = scan2[tid] - tieloc;

    double s0 = 0, s1 = 0, ss0 = 0, ss1 = 0;
    {
        const int base = tid * 4;
        int trank = tieExcl;
        #pragma unroll
        for (int k = 0; k < 4; ++k) {
            const int p = base + k;
            const unsigned key = uk[p];
            bool inc = false;
            if (key > uT) inc = true;
            else if (key == uT) { if (trank < take) inc = true; trank++; }
            if (inc) {
                float e0 = noise[((size_t)t * POP + p) * 2 + 0];
                float e1 = noise[((size_t)t * POP + p) * 2 + 1];
                float a0 = fminf(fmaxf(mu0 + sd0 * e0, -1.f), 1.f);
                float a1 = fminf(fmaxf(mu1 + sd1 * e1, -1.f), 1.f);
                s0 += a0; s1 += a1;
                ss0 += (double)a0 * a0; ss1 += (double)a1 * a1;
            }
        }
    }
    double S0, S1, SS0, SS1;
    rd[tid] = s0;  __syncthreads();
    for (int off = 512; off; off >>= 1) { if (tid < off) rd[tid] += rd[tid + off]; __syncthreads(); }
    S0 = rd[0]; __syncthreads();
    rd[tid] = s1;  __syncthreads();
    for (int off = 512; off; off >>= 1) { if (tid < off) rd[tid] += rd[tid + off]; __syncthreads(); }
    S1 = rd[0]; __syncthreads();
    rd[tid] = ss0; __syncthreads();
    for (int off = 512; off; off >>= 1) { if (tid < off) rd[tid] += rd[tid + off]; __syncthreads(); }
    SS0 = rd[0]; __syncthreads();
    rd[tid] = ss1; __syncthreads();
    for (int off = 512; off; off >>= 1) { if (tid < off) rd[tid] += rd[tid + off]; __syncthreads(); }
    SS1 = rd[0]; __syncthreads();

    if (tid == 0) {
        const double n = (double)ELITE;
        double m0 = S0 / n, m1 = S1 / n;
        double v0 = (SS0 - S0 * S0 / n) / (n - 1.0);
        double v1 = (SS1 - S1 * S1 / n) / (n - 1.0);
        float nsd0 = fmaxf((float)sqrt(fmax(v0, 0.0)), MIN_STDF);
        float nsd1 = fmaxf((float)sqrt(fmax(v1, 0.0)), MIN_STDF);
        float e0 = noise[((size_t)t * POP + argmax) * 2 + 0];
        float e1 = noise[((size_t)t * POP + argmax) * 2 + 1];
        float a0 = fminf(fmaxf(mu0 + sd0 * e0, -1.f), 1.f);
        float a1 = fminf(fmaxf(mu1 + sd1 * e1, -1.f), 1.f);
        if (maxsc > st[6]) { st[4] = a0; st[5] = a1; st[6] = maxsc; }
        st[0] = (float)m0; st[1] = (float)m1; st[2] = nsd0; st[3] = nsd1;
        if (t == ITERS - 1) { out[0] = st[4]; out[1] = st[5]; }
    }
}

// ---------------------------------------------------------------------------
extern "C" void kernel_launch(void* const* d_in, const int* in_sizes, int n_in,
                              void* d_out, int out_size, void* d_ws, size_t ws_size,
                              hipStream_t stream)
{
    const float* state = (const float*)d_in[0];
    const float* noise = (const float*)d_in[1];
    const float* W1    = (const float*)d_in[2];
    const float* b1    = (const float*)d_in[3];
    const float* W2    = (const float*)d_in[4];
    const float* b2    = (const float*)d_in[5];
    const float* W3    = (const float*)d_in[6];
    const float* b3    = (const float*)d_in[7];
    float* out = (float*)d_out;
    float* ws  = (float*)d_ws;

    const bool fast = ws_size >= WS_NEED_BYTES;

    k_base<<<dim3(2, HEADS), 256, 0, stream>>>(state, W1, b1, ws);
    if (fast) {
        unsigned short* W2S = (unsigned short*)((char*)d_ws + WS_W2S_BYTE);
        k_split<<<dim3(16, 2, HEADS), 256, 0, stream>>>(W2, W2S);
        for (int t = 0; t < ITERS; ++t) {
            k_score_mfma8<<<dim3(1280), 512, 0, stream>>>(
                noise, W1, W2S, b2, W3, ws, t);
            k_select<<<1, 1024, 0, stream>>>(noise, b3, ws, out, t);
        }
    } else {
        for (int t = 0; t < ITERS; ++t) {
            k_score<<<dim3(POP / 32, HEADS), 256, 0, stream>>>(noise, W1, W2, b2, W3, ws, t);
            k_select<<<1, 1024, 0, stream>>>(noise, b3, ws, out, t);
        }
    }
}

// Round 11
// 376.958 us; speedup vs baseline: 1.1049x; 1.1049x over previous
//
#include <hip/hip_runtime.h>
#include <math.h>

#define SDIM   256
#define HID    512
#define NH     5
#define HEADS  10
#define POP    4096
#define ITERS  4
#define ELITE  819
#define INIT_STDF 0.4f
#define MIN_STDF  0.1f

// ws layout:
//   floats: base1[10][512] @0, q_part[2][10][4096] @5120, state @87040 (7 f)
//   bytes WS_W2S_BYTE+: W2S split/transposed weights, slab layout:
//   [h][cb(2)][jc(16)] slabs of 16384 ushorts: {hi[kg4][col256][ji8], lo[...]}
#define WS_BASE1 0
#define WS_Q     5120
#define WS_STATE 87040
#define WS_W2S_BYTE 348224
#define W2S_USHORTS (HEADS * 2 * 16 * 16384)
#define WS_NEED_BYTES (WS_W2S_BYTE + (size_t)W2S_USHORTS * 2)

typedef __attribute__((ext_vector_type(4))) float f32x4;
typedef __attribute__((ext_vector_type(8))) short bf16x8;

static __device__ __forceinline__ unsigned short bf16_rne(float x) {
    unsigned b = __float_as_uint(x);
    return (unsigned short)((b + 0x7FFFu + ((b >> 16) & 1u)) >> 16);
}

// packed f32x2 -> bf16x2 (hardware cvt_pk, RNE)
static __device__ __forceinline__ unsigned pack2(float x, float y) {
    unsigned r;
    asm("v_cvt_pk_bf16_f32 %0, %1, %2" : "=v"(r) : "v"(x), "v"(y));
    return r;
}

static __device__ __forceinline__ float clip1(float x) {
    return fminf(fmaxf(x, -1.f), 1.f);
}

// ---------------------------------------------------------------------------
// Kernel 1: base1[h][j] = b1[h][j] + sum_i s[i] * W1[h][i][j]; init state
// ---------------------------------------------------------------------------
__global__ __launch_bounds__(256) void k_base(const float* __restrict__ state,
                                              const float* __restrict__ W1,
                                              const float* __restrict__ b1,
                                              float* __restrict__ ws)
{
    const int h = blockIdx.y;
    const int j = blockIdx.x * 256 + threadIdx.x;
    const float* w1h = W1 + (size_t)h * 258 * HID;
    float acc = b1[h * HID + j];
    for (int i = 0; i < SDIM; ++i)
        acc += state[i] * w1h[(size_t)i * HID + j];
    ws[WS_BASE1 + h * HID + j] = acc;

    if (h == 0 && blockIdx.x == 0 && threadIdx.x == 0) {
        float* st = ws + WS_STATE;
        st[0] = 0.f; st[1] = 0.f;
        st[2] = INIT_STDF; st[3] = INIT_STDF;
        st[4] = 0.f; st[5] = 0.f;
        st[6] = -3.402823466e38f;
    }
}

// ---------------------------------------------------------------------------
// Kernel 1b: W2 -> W2S (transpose + RNE hi/lo split). Coalesced both sides.
// ---------------------------------------------------------------------------
__global__ __launch_bounds__(256) void k_split(const float* __restrict__ W2,
                                               unsigned short* __restrict__ W2S)
{
    const int h = blockIdx.z, cb = blockIdx.y, jc = blockIdx.x;
    const int c = threadIdx.x;
    unsigned short* slab = W2S + (size_t)((h * 2 + cb) * 16 + jc) * 16384;
    #pragma unroll
    for (int jg = 0; jg < 4; ++jg) {
        unsigned hp[4], lp[4];
        #pragma unroll
        for (int i = 0; i < 4; ++i) {
            const int j = jc * 32 + jg * 8 + 2 * i;
            float v0 = W2[(size_t)(h * HID + j) * HID + cb * 256 + c];
            float v1 = W2[(size_t)(h * HID + j + 1) * HID + cb * 256 + c];
            unsigned short h0 = bf16_rne(v0), h1 = bf16_rne(v1);
            float f0 = __uint_as_float((unsigned)h0 << 16);
            float f1 = __uint_as_float((unsigned)h1 << 16);
            unsigned short l0 = bf16_rne(v0 - f0), l1 = bf16_rne(v1 - f1);
            hp[i] = (unsigned)h0 | ((unsigned)h1 << 16);
            lp[i] = (unsigned)l0 | ((unsigned)l1 << 16);
        }
        uint4 HV, LV;
        HV.x = hp[0]; HV.y = hp[1]; HV.z = hp[2]; HV.w = hp[3];
        LV.x = lp[0]; LV.y = lp[1]; LV.z = lp[2]; LV.w = lp[3];
        *(uint4*)&slab[jg * 2048 + c * 8] = HV;
        *(uint4*)&slab[8192 + jg * 2048 + c * 8] = LV;
    }
}

// ---------------------------------------------------------------------------
// Kernel 2 (R9 structure, m/n-swapped waves): 512 thr / 8 waves = 64 rows x
// 256 cols. Wave = 32 rows x 64 cols (wr x wc grid 2x4), acc[2][4] = 32 AGPR
// (occupancy preserved: unified <=128 -> 4 waves/SIMD). Per chunk per wave:
// 4 A ds_read_b128 (HALF of R9 -> LDS pipe ~20us < 31us MFMA floor) +
// 8 B global loads (L2-resident, 2x R9 but different pipe) + 24 MFMA in 3
// passes of 8 independent. A computed by thr 0-255 into LDS dbuf; one
// barrier/chunk; setprio around MFMAs.
// ---------------------------------------------------------------------------
__global__ __launch_bounds__(512, 4) void k_score_mfma9(
    const float* __restrict__ noise, const float* __restrict__ W1,
    const unsigned short* __restrict__ W2S,
    const float* __restrict__ b2, const float* __restrict__ W3,
    float* __restrict__ ws, int t)
{
    __shared__ unsigned short As[2][4096];   // dbuf: {hi[kg4][row64][ji8], lo}
    __shared__ float red[4][64];

    const int tid = threadIdx.x;
    const int bid = blockIdx.x;
    // bijective XCD remap (1280 = 8*160): consecutive w share (h,cb) panel
    const int w = (bid & 7) * 160 + (bid >> 3);
    const int h = w >> 7;
    const int rem = w & 127;
    const int cb = rem >> 6;
    const int rs = rem & 63;            // row-stripe of 64

    const int lane = tid & 63;
    const int wv = tid >> 6;            // 0..7
    const int wr = wv >> 2;             // row group (32 rows)
    const int wc = wv & 3;              // col group (64 cols)
    const int l15 = lane & 15, lk = lane >> 4;

    // computeA role (threads 0..255): row = tid&63, kg = (tid>>6)&3
    const int arow = tid & 63;
    const int akg = (tid >> 6) & 3;

    const float* st = ws + WS_STATE;
    const float mu0 = st[0], mu1 = st[1], sd0 = st[2], sd1 = st[3];
    float2 e = *(const float2*)&noise[((size_t)t * POP + rs * 64 + arow) * 2];
    const float a0 = clip1(mu0 + sd0 * e.x);
    const float a1 = clip1(mu1 + sd1 * e.y);

    const float* base1 = ws + WS_BASE1 + h * HID;
    const float* w1u = W1 + ((size_t)h * 258 + 256) * HID;
    const float* w1v = W1 + ((size_t)h * 258 + 257) * HID;
    const unsigned short* bslab = W2S + (size_t)((h * 2 + cb) * 16) * 16384;
    // B frag: kg=lk, col = wc*64 + n*16 + l15 -> bco + n*128 (lo at +8192)
    const int bco = lk * 2048 + (wc * 64 + l15) * 8;
    // A frag: kg=lk, row = wr*32 + m*16 + l15 -> ar0 + m*128 (lo at +2048)
    const int ar0 = lk * 512 + (wr * 32 + l15) * 8;

    // compute A chunk jc (rank-2 + relu + cvt_pk hi/lo split) into As[buf]
    auto computeA = [&](int jc, int buf) {
        if (tid < 256) {
            const int j = jc * 32 + akg * 8;
            f32x4 b0 = *(const f32x4*)&base1[j];
            f32x4 b1v = *(const f32x4*)&base1[j + 4];
            f32x4 u0 = *(const f32x4*)&w1u[j];
            f32x4 u1 = *(const f32x4*)&w1u[j + 4];
            f32x4 v0 = *(const f32x4*)&w1v[j];
            f32x4 v1 = *(const f32x4*)&w1v[j + 4];
            float hv[8];
            #pragma unroll
            for (int i = 0; i < 4; ++i) {
                hv[i]     = fmaxf(b0[i] + a0 * u0[i] + a1 * v0[i], 0.f);
                hv[4 + i] = fmaxf(b1v[i] + a0 * u1[i] + a1 * v1[i], 0.f);
            }
            unsigned ph[4], pl[4];
            #pragma unroll
            for (int i = 0; i < 4; ++i) {
                ph[i] = pack2(hv[2 * i], hv[2 * i + 1]);
                float fx = __uint_as_float(ph[i] << 16);
                float fy = __uint_as_float(ph[i] & 0xFFFF0000u);
                pl[i] = pack2(hv[2 * i] - fx, hv[2 * i + 1] - fy);
            }
            uint4 HV, LV;
            HV.x = ph[0]; HV.y = ph[1]; HV.z = ph[2]; HV.w = ph[3];
            LV.x = pl[0]; LV.y = pl[1]; LV.z = pl[2]; LV.w = pl[3];
            *(uint4*)&As[buf][akg * 512 + arow * 8] = HV;
            *(uint4*)&As[buf][2048 + akg * 512 + arow * 8] = LV;
        }
    };

    f32x4 acc[2][4];
    #pragma unroll
    for (int m = 0; m < 2; ++m)
        #pragma unroll
        for (int n = 0; n < 4; ++n)
            acc[m][n] = (f32x4){0.f, 0.f, 0.f, 0.f};

    // prologue: A(0) into buf 0; B(0) into regs
    computeA(0, 0);
    bf16x8 BH[4], BL[4];
    #pragma unroll
    for (int n = 0; n < 4; ++n) {
        BH[n] = *(const bf16x8*)(bslab + bco + n * 128);
        BL[n] = *(const bf16x8*)(bslab + 8192 + bco + n * 128);
    }
    __syncthreads();

    int cur = 0;
    #pragma unroll 1
    for (int kc = 0; kc < 16; ++kc) {
        // A fragments from shared tile (4 x ds_read_b128)
        bf16x8 AH[2], AL[2];
        #pragma unroll
        for (int m = 0; m < 2; ++m) {
            const int ad = ar0 + m * 128;
            AH[m] = *(const bf16x8*)&As[cur][ad];
            AL[m] = *(const bf16x8*)&As[cur][2048 + ad];
        }
        // prefetch next-chunk B (clamped; hidden under this chunk's MFMAs)
        const int nc = (kc < 15) ? kc + 1 : 15;
        const unsigned short* bnc = bslab + (size_t)nc * 16384;
        bf16x8 nBH[4], nBL[4];
        #pragma unroll
        for (int n = 0; n < 4; ++n) {
            nBH[n] = *(const bf16x8*)(bnc + bco + n * 128);
            nBL[n] = *(const bf16x8*)(bnc + 8192 + bco + n * 128);
        }
        // 3 passes of 8 independent MFMAs
        __builtin_amdgcn_s_setprio(1);
        #pragma unroll
        for (int m = 0; m < 2; ++m)
            #pragma unroll
            for (int n = 0; n < 4; ++n)
                acc[m][n] = __builtin_amdgcn_mfma_f32_16x16x32_bf16(
                    AH[m], BH[n], acc[m][n], 0, 0, 0);
        #pragma unroll
        for (int m = 0; m < 2; ++m)
            #pragma unroll
            for (int n = 0; n < 4; ++n)
                acc[m][n] = __builtin_amdgcn_mfma_f32_16x16x32_bf16(
                    AL[m], BH[n], acc[m][n], 0, 0, 0);
        #pragma unroll
        for (int m = 0; m < 2; ++m)
            #pragma unroll
            for (int n = 0; n < 4; ++n)
                acc[m][n] = __builtin_amdgcn_mfma_f32_16x16x32_bf16(
                    AH[m], BL[n], acc[m][n], 0, 0, 0);
        __builtin_amdgcn_s_setprio(0);
        // next A tile into the other buffer, then one barrier
        computeA(nc, cur ^ 1);
        __syncthreads();
        #pragma unroll
        for (int n = 0; n < 4; ++n) { BH[n] = nBH[n]; BL[n] = nBL[n]; }
        cur ^= 1;
    }

    // epilogue: q_part = sum over this block's 256 cols of
    //           relu(acc + b2[col]) * W3[col]
    // C layout (m89): col = l15, row = lk*4 + reg (+16 per m-frag)
    float qp[2][4];
    #pragma unroll
    for (int m = 0; m < 2; ++m)
        #pragma unroll
        for (int r = 0; r < 4; ++r) qp[m][r] = 0.f;
    #pragma unroll
    for (int n = 0; n < 4; ++n) {
        int gcol = cb * 256 + wc * 64 + n * 16 + l15;
        float b2v = b2[h * HID + gcol];
        float w3v = W3[h * HID + gcol];
        #pragma unroll
        for (int m = 0; m < 2; ++m)
            #pragma unroll
            for (int r = 0; r < 4; ++r)
                qp[m][r] += fmaxf(acc[m][n][r] + b2v, 0.f) * w3v;
    }
    #pragma unroll
    for (int m = 0; m < 2; ++m)
        #pragma unroll
        for (int r = 0; r < 4; ++r) {
            float v = qp[m][r];
            v += __shfl_xor(v, 1);
            v += __shfl_xor(v, 2);
            v += __shfl_xor(v, 4);
            v += __shfl_xor(v, 8);
            if (l15 == 0) red[wc][wr * 32 + m * 16 + lk * 4 + r] = v;
        }
    __syncthreads();
    if (tid < 64) {
        float q = red[0][tid] + red[1][tid] + red[2][tid] + red[3][tid];
        ws[WS_Q + (size_t)(cb * HEADS + h) * POP + rs * 64 + tid] = q;
    }
}

// ---------------------------------------------------------------------------
// Kernel 2 (fp32 fallback, used only if ws too small): writes part0, zeroes
// part1 so k_select's partial-sum read stays correct.
// ---------------------------------------------------------------------------
__global__ __launch_bounds__(256) void k_score(const float* __restrict__ noise,
                                               const float* __restrict__ W1,
                                               const float* __restrict__ W2,
                                               const float* __restrict__ b2,
                                               const float* __restrict__ W3,
                                               float* __restrict__ ws, int t)
{
    __shared__ float h1[32][HID];
    __shared__ float a0s[32], a1s[32];
    __shared__ float red[2][16][2];

    const int tid = threadIdx.x;
    const int h   = blockIdx.y;
    const int p0  = blockIdx.x * 32;

    if (tid < 32) {
        const float* st = ws + WS_STATE;
        const int p = p0 + tid;
        float e0 = noise[((size_t)t * POP + p) * 2 + 0];
        float e1 = noise[((size_t)t * POP + p) * 2 + 1];
        a0s[tid] = fminf(fmaxf(st[0] + st[2] * e0, -1.f), 1.f);
        a1s[tid] = fminf(fmaxf(st[1] + st[3] * e1, -1.f), 1.f);
    }
    __syncthreads();

    const float* base1 = ws + WS_BASE1 + h * HID;
    const float* w1u = W1 + ((size_t)h * 258 + 256) * HID;
    const float* w1v = W1 + ((size_t)h * 258 + 257) * HID;
    #pragma unroll
    for (int jj = 0; jj < 2; ++jj) {
        int j = tid + jj * 256;
        float bb = base1[j], uu = w1u[j], vv = w1v[j];
        #pragma unroll
        for (int p = 0; p < 32; ++p)
            h1[p][j] = fmaxf(bb + a0s[p] * uu + a1s[p] * vv, 0.f);
    }
    __syncthreads();

    const int pg = tid >> 7;
    const int kl = tid & 127;
    const float* W2h = W2 + (size_t)h * HID * HID + kl;

    float acc[16][4];
    #pragma unroll
    for (int p = 0; p < 16; ++p)
        #pragma unroll
        for (int dk = 0; dk < 4; ++dk) acc[p][dk] = 0.f;

    for (int j0 = 0; j0 < HID; j0 += 4) {
        float w[4][4];
        #pragma unroll
        for (int dj = 0; dj < 4; ++dj)
            #pragma unroll
            for (int dk = 0; dk < 4; ++dk)
                w[dj][dk] = W2h[(size_t)(j0 + dj) * HID + dk * 128];
        #pragma unroll
        for (int p = 0; p < 16; ++p) {
            const float4 hv = *(const float4*)&h1[pg * 16 + p][j0];
            #pragma unroll
            for (int dk = 0; dk < 4; ++dk)
                acc[p][dk] += hv.x * w[0][dk] + hv.y * w[1][dk]
                            + hv.z * w[2][dk] + hv.w * w[3][dk];
        }
    }

    float b2v[4], w3v[4];
    #pragma unroll
    for (int dk = 0; dk < 4; ++dk) {
        b2v[dk] = b2[h * HID + kl + dk * 128];
        w3v[dk] = W3[h * HID + kl + dk * 128];
    }
    const int wid  = tid >> 6;
    const int lane = tid & 63;
    const int wig  = wid & 1;
    #pragma unroll
    for (int p = 0; p < 16; ++p) {
        float v = 0.f;
        #pragma unroll
        for (int dk = 0; dk < 4; ++dk)
            v += fmaxf(acc[p][dk] + b2v[dk], 0.f) * w3v[dk];
        #pragma unroll
        for (int off = 32; off; off >>= 1) v += __shfl_down(v, off);
        if (lane == 0) red[pg][p][wig] = v;
    }
    __syncthreads();
    if (tid < 32) {
        int pp = tid & 15, g = tid >> 4;
        ws[WS_Q + (size_t)h * POP + p0 + g * 16 + pp] =
            red[g][pp][0] + red[g][pp][1];
        ws[WS_Q + (size_t)(HEADS + h) * POP + p0 + g * 16 + pp] = 0.f;
    }
}

// ---------------------------------------------------------------------------
// Kernel 3 (1024 threads): scores from q partials (+b3), exact top-819
// radix select, elite mean/std (ddof=1, double accum), best_a update.
// ---------------------------------------------------------------------------
__global__ __launch_bounds__(1024) void k_select(const float* __restrict__ noise,
                                                 const float* __restrict__ b3,
                                                 float* __restrict__ ws,
                                                 float* __restrict__ out, int t)
{
    __shared__ float    sc[POP];        // 16 KB
    __shared__ unsigned uk[POP];        // 16 KB
    __shared__ unsigned hist[256];
    __shared__ int      scan2[1024];
    __shared__ float    rf[1024];
    __shared__ int      ri_[1024];
    __shared__ double   rd[1024];
    __shared__ unsigned s_prefix;
    __shared__ int      s_r;

    const int tid = threadIdx.x;
    const float* q = ws + WS_Q;
    float* st = ws + WS_STATE;
    const float mu0 = st[0], mu1 = st[1], sd0 = st[2], sd1 = st[3];

    // scores = mean_h min(q1,q2); q[h] = part0 + part1 + b3[h]
    {
        const int p = tid * 4;
        f32x4 s = (f32x4){0.f, 0.f, 0.f, 0.f};
        #pragma unroll
        for (int hh = 0; hh < NH; ++hh) {
            f32x4 qa0 = *(const f32x4*)&q[(size_t)hh * POP + p];
            f32x4 qa1 = *(const f32x4*)&q[(size_t)(HEADS + hh) * POP + p];
            f32x4 qb0 = *(const f32x4*)&q[(size_t)(NH + hh) * POP + p];
            f32x4 qb1 = *(const f32x4*)&q[(size_t)(HEADS + NH + hh) * POP + p];
            float ba = b3[hh], bb = b3[NH + hh];
            #pragma unroll
            for (int i = 0; i < 4; ++i)
                s[i] += fminf(qa0[i] + qa1[i] + ba, qb0[i] + qb1[i] + bb);
        }
        #pragma unroll
        for (int i = 0; i < 4; ++i) {
            float v = s[i] * 0.2f;
            sc[p + i] = v;
            unsigned b = __float_as_uint(v);
            uk[p + i] = (b & 0x80000000u) ? ~b : (b | 0x80000000u);
        }
    }
    __syncthreads();

    // max + argmax (lowest index on ties); threads own disjoint ascending
    // index ranges so strict '>' keeps the lowest index within a thread.
    float mv = -3.402823466e38f; int mi = 0;
    #pragma unroll
    for (int k = 0; k < 4; ++k) {
        const int p = tid * 4 + k;
        float v = sc[p];
        if (v > mv) { mv = v; mi = p; }
    }
    rf[tid] = mv; ri_[tid] = mi;
    __syncthreads();
    for (int off = 512; off; off >>= 1) {
        if (tid < off) {
            float ov = rf[tid + off]; int oi = ri_[tid + off];
            if (ov > rf[tid] || (ov == rf[tid] && oi < ri_[tid])) {
                rf[tid] = ov; ri_[tid] = oi;
            }
        }
        __syncthreads();
    }
    const float maxsc = rf[0];
    const int argmax = ri_[0];
    __syncthreads();

    // radix select with parallel suffix-scan digit pick
    unsigned prefix = 0; int r = ELITE;
    for (int shift = 24; shift >= 0; shift -= 8) {
        if (tid < 256) hist[tid] = 0;
        __syncthreads();
        const unsigned himask = (shift < 24) ? (0xFFFFFFFFu << (shift + 8)) : 0u;
        for (int p = tid; p < POP; p += 1024) {
            unsigned key = uk[p];
            if ((key & himask) == prefix)
                atomicAdd(&hist[(key >> shift) & 255u], 1u);
        }
        __syncthreads();
        scan2[tid] = (tid < 256) ? (int)hist[tid] : 0;
        __syncthreads();
        for (int off = 1; off < 256; off <<= 1) {
            int v = (tid < 256 && tid + off < 256) ? scan2[tid + off] : 0;
            __syncthreads();
            if (tid < 256) scan2[tid] += v;
            __syncthreads();
        }
        if (tid < 256) {
            int above = (tid < 255) ? scan2[tid + 1] : 0;
            if (scan2[tid] >= r && above < r) {
                s_prefix = prefix | ((unsigned)tid << shift);
                s_r = r - above;
            }
        }
        __syncthreads();
        prefix = s_prefix; r = s_r;
        __syncthreads();
    }
    const unsigned uT = prefix;
    const int take = r;

    // tie ranks (index order) via prefix scan over contiguous 4-chunks
    int tieloc = 0;
    {
        const int base = tid * 4;
        #pragma unroll
        for (int k = 0; k < 4; ++k) if (uk[base + k] == uT) tieloc++;
    }
    scan2[tid] = tieloc;
    __syncthreads();
    for (int off = 1; off < 1024; off <<= 1) {
        int v = (tid >= off) ? scan2[tid - off] : 0;
        __syncthreads();
        scan2[tid] += v;
        __syncthreads();
    }
    const int tieExcl = scan2[tid] - tieloc;

    double s0 = 0, s1 = 0, ss0 = 0, ss1 = 0;
    {
        const int base = tid * 4;
        int trank = tieExcl;
        #pragma unroll
        for (int k = 0; k < 4; ++k) {
            const int p = base + k;
            const unsigned key = uk[p];
            bool inc = false;
            if (key > uT) inc = true;
            else if (key == uT) { if (trank < take) inc = true; trank++; }
            if (inc) {
                float e0 = noise[((size_t)t * POP + p) * 2 + 0];
                float e1 = noise[((size_t)t * POP + p) * 2 + 1];
                float a0 = fminf(fmaxf(mu0 + sd0 * e0, -1.f), 1.f);
                float a1 = fminf(fmaxf(mu1 + sd1 * e1, -1.f), 1.f);
                s0 += a0; s1 += a1;
                ss0 += (double)a0 * a0; ss1 += (double)a1 * a1;
            }
        }
    }
    double S0, S1, SS0, SS1;
    rd[tid] = s0;  __syncthreads();
    for (int off = 512; off; off >>= 1) { if (tid < off) rd[tid] += rd[tid + off]; __syncthreads(); }
    S0 = rd[0]; __syncthreads();
    rd[tid] = s1;  __syncthreads();
    for (int off = 512; off; off >>= 1) { if (tid < off) rd[tid] += rd[tid + off]; __syncthreads(); }
    S1 = rd[0]; __syncthreads();
    rd[tid] = ss0; __syncthreads();
    for (int off = 512; off; off >>= 1) { if (tid < off) rd[tid] += rd[tid + off]; __syncthreads(); }
    SS0 = rd[0]; __syncthreads();
    rd[tid] = ss1; __syncthreads();
    for (int off = 512; off; off >>= 1) { if (tid < off) rd[tid] += rd[tid + off]; __syncthreads(); }
    SS1 = rd[0]; __syncthreads();

    if (tid == 0) {
        const double n = (double)ELITE;
        double m0 = S0 / n, m1 = S1 / n;
        double v0 = (SS0 - S0 * S0 / n) / (n - 1.0);
        double v1 = (SS1 - S1 * S1 / n) / (n - 1.0);
        float nsd0 = fmaxf((float)sqrt(fmax(v0, 0.0)), MIN_STDF);
        float nsd1 = fmaxf((float)sqrt(fmax(v1, 0.0)), MIN_STDF);
        float e0 = noise[((size_t)t * POP + argmax) * 2 + 0];
        float e1 = noise[((size_t)t * POP + argmax) * 2 + 1];
        float a0 = fminf(fmaxf(mu0 + sd0 * e0, -1.f), 1.f);
        float a1 = fminf(fmaxf(mu1 + sd1 * e1, -1.f), 1.f);
        if (maxsc > st[6]) { st[4] = a0; st[5] = a1; st[6] = maxsc; }
        st[0] = (float)m0; st[1] = (float)m1; st[2] = nsd0; st[3] = nsd1;
        if (t == ITERS - 1) { out[0] = st[4]; out[1] = st[5]; }
    }
}

// ---------------------------------------------------------------------------
extern "C" void kernel_launch(void* const* d_in, const int* in_sizes, int n_in,
                              void* d_out, int out_size, void* d_ws, size_t ws_size,
                              hipStream_t stream)
{
    const float* state = (const float*)d_in[0];
    const float* noise = (const float*)d_in[1];
    const float* W1    = (const float*)d_in[2];
    const float* b1    = (const float*)d_in[3];
    const float* W2    = (const float*)d_in[4];
    const float* b2    = (const float*)d_in[5];
    const float* W3    = (const float*)d_in[6];
    const float* b3    = (const float*)d_in[7];
    float* out = (float*)d_out;
    float* ws  = (float*)d_ws;

    const bool fast = ws_size >= WS_NEED_BYTES;

    k_base<<<dim3(2, HEADS), 256, 0, stream>>>(state, W1, b1, ws);
    if (fast) {
        unsigned short* W2S = (unsigned short*)((char*)d_ws + WS_W2S_BYTE);
        k_split<<<dim3(16, 2, HEADS), 256, 0, stream>>>(W2, W2S);
        for (int t = 0; t < ITERS; ++t) {
            k_score_mfma9<<<dim3(1280), 512, 0, stream>>>(
                noise, W1, W2S, b2, W3, ws, t);
            k_select<<<1, 1024, 0, stream>>>(noise, b3, ws, out, t);
        }
    } else {
        for (int t = 0; t < ITERS; ++t) {
            k_score<<<dim3(POP / 32, HEADS), 256, 0, stream>>>(noise, W1, W2, b2, W3, ws, t);
            k_select<<<1, 1024, 0, stream>>>(noise, b3, ws, out, t);
        }
    }
}

// Round 12
// 332.097 us; speedup vs baseline: 1.2542x; 1.1351x over previous
//
#include <hip/hip_runtime.h>
#include <math.h>

#define SDIM   256
#define HID    512
#define NH     5
#define HEADS  10
#define POP    4096
#define ITERS  4
#define ELITE  819
#define INIT_STDF 0.4f
#define MIN_STDF  0.1f

// ws layout:
//   floats: base1[10][512] @0, q_part[2][10][4096] @5120, state @87040 (7 f)
//   bytes WS_W2S_BYTE+: W2S split/transposed weights, slab layout:
//   [h][cb(2)][jc(16)] slabs of 16384 ushorts: {hi[kg4][col256][ji8], lo[...]}
#define WS_BASE1 0
#define WS_Q     5120
#define WS_STATE 87040
#define WS_W2S_BYTE 348224
#define W2S_USHORTS (HEADS * 2 * 16 * 16384)
#define WS_NEED_BYTES (WS_W2S_BYTE + (size_t)W2S_USHORTS * 2)

typedef __attribute__((ext_vector_type(4))) float f32x4;
typedef __attribute__((ext_vector_type(8))) short bf16x8;

static __device__ __forceinline__ unsigned short bf16_rne(float x) {
    unsigned b = __float_as_uint(x);
    return (unsigned short)((b + 0x7FFFu + ((b >> 16) & 1u)) >> 16);
}

// packed f32x2 -> bf16x2 (hardware cvt_pk, RNE)
static __device__ __forceinline__ unsigned pack2(float x, float y) {
    unsigned r;
    asm("v_cvt_pk_bf16_f32 %0, %1, %2" : "=v"(r) : "v"(x), "v"(y));
    return r;
}

static __device__ __forceinline__ float clip1(float x) {
    return fminf(fmaxf(x, -1.f), 1.f);
}

// ---------------------------------------------------------------------------
// Kernel 1: base1[h][j] = b1[h][j] + sum_i s[i] * W1[h][i][j]; init state
// ---------------------------------------------------------------------------
__global__ __launch_bounds__(256) void k_base(const float* __restrict__ state,
                                              const float* __restrict__ W1,
                                              const float* __restrict__ b1,
                                              float* __restrict__ ws)
{
    const int h = blockIdx.y;
    const int j = blockIdx.x * 256 + threadIdx.x;
    const float* w1h = W1 + (size_t)h * 258 * HID;
    float acc = b1[h * HID + j];
    for (int i = 0; i < SDIM; ++i)
        acc += state[i] * w1h[(size_t)i * HID + j];
    ws[WS_BASE1 + h * HID + j] = acc;

    if (h == 0 && blockIdx.x == 0 && threadIdx.x == 0) {
        float* st = ws + WS_STATE;
        st[0] = 0.f; st[1] = 0.f;
        st[2] = INIT_STDF; st[3] = INIT_STDF;
        st[4] = 0.f; st[5] = 0.f;
        st[6] = -3.402823466e38f;
    }
}

// ---------------------------------------------------------------------------
// Kernel 1b: W2 -> W2S (transpose + RNE hi/lo split). Coalesced both sides.
// ---------------------------------------------------------------------------
__global__ __launch_bounds__(256) void k_split(const float* __restrict__ W2,
                                               unsigned short* __restrict__ W2S)
{
    const int h = blockIdx.z, cb = blockIdx.y, jc = blockIdx.x;
    const int c = threadIdx.x;
    unsigned short* slab = W2S + (size_t)((h * 2 + cb) * 16 + jc) * 16384;
    #pragma unroll
    for (int jg = 0; jg < 4; ++jg) {
        unsigned hp[4], lp[4];
        #pragma unroll
        for (int i = 0; i < 4; ++i) {
            const int j = jc * 32 + jg * 8 + 2 * i;
            float v0 = W2[(size_t)(h * HID + j) * HID + cb * 256 + c];
            float v1 = W2[(size_t)(h * HID + j + 1) * HID + cb * 256 + c];
            unsigned short h0 = bf16_rne(v0), h1 = bf16_rne(v1);
            float f0 = __uint_as_float((unsigned)h0 << 16);
            float f1 = __uint_as_float((unsigned)h1 << 16);
            unsigned short l0 = bf16_rne(v0 - f0), l1 = bf16_rne(v1 - f1);
            hp[i] = (unsigned)h0 | ((unsigned)h1 << 16);
            lp[i] = (unsigned)l0 | ((unsigned)l1 << 16);
        }
        uint4 HV, LV;
        HV.x = hp[0]; HV.y = hp[1]; HV.z = hp[2]; HV.w = hp[3];
        LV.x = lp[0]; LV.y = lp[1]; LV.z = lp[2]; LV.w = lp[3];
        *(uint4*)&slab[jg * 2048 + c * 8] = HV;
        *(uint4*)&slab[8192 + jg * 2048 + c * 8] = LV;
    }
}

// ---------------------------------------------------------------------------
// Kernel 2 (R9 structure, VALU-balanced): 512 thr / 8 waves = 64 rows x
// 256 cols; wave = 64 rows x 32 cols, acc[4][2] = 32 AGPR (unified <=128 ->
// 4 waves/SIMD — the R9 occupancy win). A computed into LDS dbuf by ALL 512
// threads (4 elem each, branch-free -> loads hoist, VALU phase halves vs
// R9's 256-thread version). B direct global->VGPR from L2-resident W2S with
// next-chunk prefetch. One barrier/chunk; setprio(1) around the 24 MFMAs.
// ---------------------------------------------------------------------------
__global__ __launch_bounds__(512, 4) void k_score_mfma10(
    const float* __restrict__ noise, const float* __restrict__ W1,
    const unsigned short* __restrict__ W2S,
    const float* __restrict__ b2, const float* __restrict__ W3,
    float* __restrict__ ws, int t)
{
    __shared__ unsigned short As[2][4096];   // dbuf: {hi[kg4][row64][ji8], lo}
    __shared__ float red[8][64];

    const int tid = threadIdx.x;
    const int bid = blockIdx.x;
    // bijective XCD remap (1280 = 8*160): consecutive w share (h,cb) panel
    const int w = (bid & 7) * 160 + (bid >> 3);
    const int h = w >> 7;
    const int rem = w & 127;
    const int cb = rem >> 6;
    const int rs = rem & 63;            // row-stripe of 64

    const int lane = tid & 63;
    const int wv = tid >> 6;            // 0..7 -> 32-col strip
    const int l15 = lane & 15, lk = lane >> 4;

    // computeA role (ALL 512 threads): row = tid&63, kg = (tid>>6)&3,
    // half = tid>>8 -> each thread produces 4 contiguous elements.
    const int arow = tid & 63;
    const int akg = (tid >> 6) & 3;
    const int ahalf = tid >> 8;         // 0/1

    const float* st = ws + WS_STATE;
    const float mu0 = st[0], mu1 = st[1], sd0 = st[2], sd1 = st[3];
    float2 e = *(const float2*)&noise[((size_t)t * POP + rs * 64 + arow) * 2];
    const float a0 = clip1(mu0 + sd0 * e.x);
    const float a1 = clip1(mu1 + sd1 * e.y);

    const float* base1 = ws + WS_BASE1 + h * HID;
    const float* w1u = W1 + ((size_t)h * 258 + 256) * HID;
    const float* w1v = W1 + ((size_t)h * 258 + 257) * HID;
    const unsigned short* bslab = W2S + (size_t)((h * 2 + cb) * 16) * 16384;
    // B frag: kg=lk, col = wv*32 + n*16 + l15 (lo at +8192)
    const int bco = lk * 2048 + (wv * 32 + l15) * 8;

    // compute A chunk jc (rank-2 + relu + cvt_pk hi/lo split) into As[buf]
    auto computeA = [&](int jc, int buf) {
        const int j = jc * 32 + akg * 8 + ahalf * 4;
        f32x4 b0 = *(const f32x4*)&base1[j];
        f32x4 u0 = *(const f32x4*)&w1u[j];
        f32x4 v0 = *(const f32x4*)&w1v[j];
        float hv[4];
        #pragma unroll
        for (int i = 0; i < 4; ++i)
            hv[i] = fmaxf(b0[i] + a0 * u0[i] + a1 * v0[i], 0.f);
        unsigned ph[2], pl[2];
        #pragma unroll
        for (int i = 0; i < 2; ++i) {
            ph[i] = pack2(hv[2 * i], hv[2 * i + 1]);
            float fx = __uint_as_float(ph[i] << 16);
            float fy = __uint_as_float(ph[i] & 0xFFFF0000u);
            pl[i] = pack2(hv[2 * i] - fx, hv[2 * i + 1] - fy);
        }
        uint2 HV, LV;
        HV.x = ph[0]; HV.y = ph[1];
        LV.x = pl[0]; LV.y = pl[1];
        const int ao = akg * 512 + arow * 8 + ahalf * 4;
        *(uint2*)&As[buf][ao] = HV;
        *(uint2*)&As[buf][2048 + ao] = LV;
    };

    f32x4 acc[4][2];
    #pragma unroll
    for (int m = 0; m < 4; ++m)
        #pragma unroll
        for (int n = 0; n < 2; ++n)
            acc[m][n] = (f32x4){0.f, 0.f, 0.f, 0.f};

    // prologue: A(0) into buf 0; B(0) into regs
    computeA(0, 0);
    bf16x8 BH[2], BL[2];
    #pragma unroll
    for (int n = 0; n < 2; ++n) {
        BH[n] = *(const bf16x8*)(bslab + bco + n * 128);
        BL[n] = *(const bf16x8*)(bslab + 8192 + bco + n * 128);
    }
    __syncthreads();

    int cur = 0;
    #pragma unroll 1
    for (int kc = 0; kc < 16; ++kc) {
        // A fragments from shared tile (8 x ds_read_b128, conflict-free)
        bf16x8 AH[4], AL[4];
        #pragma unroll
        for (int m = 0; m < 4; ++m) {
            const int ad = lk * 512 + (m * 16 + l15) * 8;
            AH[m] = *(const bf16x8*)&As[cur][ad];
            AL[m] = *(const bf16x8*)&As[cur][2048 + ad];
        }
        // prefetch next-chunk B (clamped; hidden under this chunk's MFMAs)
        const int nc = (kc < 15) ? kc + 1 : 15;
        const unsigned short* bnc = bslab + (size_t)nc * 16384;
        bf16x8 nBH[2], nBL[2];
        #pragma unroll
        for (int n = 0; n < 2; ++n) {
            nBH[n] = *(const bf16x8*)(bnc + bco + n * 128);
            nBL[n] = *(const bf16x8*)(bnc + 8192 + bco + n * 128);
        }
        // 3 passes of 8 independent MFMAs
        __builtin_amdgcn_s_setprio(1);
        #pragma unroll
        for (int m = 0; m < 4; ++m)
            #pragma unroll
            for (int n = 0; n < 2; ++n)
                acc[m][n] = __builtin_amdgcn_mfma_f32_16x16x32_bf16(
                    AH[m], BH[n], acc[m][n], 0, 0, 0);
        #pragma unroll
        for (int m = 0; m < 4; ++m)
            #pragma unroll
            for (int n = 0; n < 2; ++n)
                acc[m][n] = __builtin_amdgcn_mfma_f32_16x16x32_bf16(
                    AL[m], BH[n], acc[m][n], 0, 0, 0);
        #pragma unroll
        for (int m = 0; m < 4; ++m)
            #pragma unroll
            for (int n = 0; n < 2; ++n)
                acc[m][n] = __builtin_amdgcn_mfma_f32_16x16x32_bf16(
                    AH[m], BL[n], acc[m][n], 0, 0, 0);
        __builtin_amdgcn_s_setprio(0);
        // next A tile into the other buffer, then one barrier
        computeA(nc, cur ^ 1);
        __syncthreads();
        #pragma unroll
        for (int n = 0; n < 2; ++n) { BH[n] = nBH[n]; BL[n] = nBL[n]; }
        cur ^= 1;
    }

    // epilogue: q_part = sum over this block's 256 cols of
    //           relu(acc + b2[col]) * W3[col]
    // C layout (m89): col = l15, row = lk*4 + reg (+16 per m-frag)
    float qp[4][4];
    #pragma unroll
    for (int m = 0; m < 4; ++m)
        #pragma unroll
        for (int r = 0; r < 4; ++r) qp[m][r] = 0.f;
    #pragma unroll
    for (int n = 0; n < 2; ++n) {
        int gcol = cb * 256 + wv * 32 + n * 16 + l15;
        float b2v = b2[h * HID + gcol];
        float w3v = W3[h * HID + gcol];
        #pragma unroll
        for (int m = 0; m < 4; ++m)
            #pragma unroll
            for (int r = 0; r < 4; ++r)
                qp[m][r] += fmaxf(acc[m][n][r] + b2v, 0.f) * w3v;
    }
    #pragma unroll
    for (int m = 0; m < 4; ++m)
        #pragma unroll
        for (int r = 0; r < 4; ++r) {
            float v = qp[m][r];
            v += __shfl_xor(v, 1);
            v += __shfl_xor(v, 2);
            v += __shfl_xor(v, 4);
            v += __shfl_xor(v, 8);
            if (l15 == 0) red[wv][m * 16 + lk * 4 + r] = v;
        }
    __syncthreads();
    if (tid < 64) {
        float q = 0.f;
        #pragma unroll
        for (int s = 0; s < 8; ++s) q += red[s][tid];
        ws[WS_Q + (size_t)(cb * HEADS + h) * POP + rs * 64 + tid] = q;
    }
}

// ---------------------------------------------------------------------------
// Kernel 2 (fp32 fallback, used only if ws too small): writes part0, zeroes
// part1 so k_select's partial-sum read stays correct.
// ---------------------------------------------------------------------------
__global__ __launch_bounds__(256) void k_score(const float* __restrict__ noise,
                                               const float* __restrict__ W1,
                                               const float* __restrict__ W2,
                                               const float* __restrict__ b2,
                                               const float* __restrict__ W3,
                                               float* __restrict__ ws, int t)
{
    __shared__ float h1[32][HID];
    __shared__ float a0s[32], a1s[32];
    __shared__ float red[2][16][2];

    const int tid = threadIdx.x;
    const int h   = blockIdx.y;
    const int p0  = blockIdx.x * 32;

    if (tid < 32) {
        const float* st = ws + WS_STATE;
        const int p = p0 + tid;
        float e0 = noise[((size_t)t * POP + p) * 2 + 0];
        float e1 = noise[((size_t)t * POP + p) * 2 + 1];
        a0s[tid] = fminf(fmaxf(st[0] + st[2] * e0, -1.f), 1.f);
        a1s[tid] = fminf(fmaxf(st[1] + st[3] * e1, -1.f), 1.f);
    }
    __syncthreads();

    const float* base1 = ws + WS_BASE1 + h * HID;
    const float* w1u = W1 + ((size_t)h * 258 + 256) * HID;
    const float* w1v = W1 + ((size_t)h * 258 + 257) * HID;
    #pragma unroll
    for (int jj = 0; jj < 2; ++jj) {
        int j = tid + jj * 256;
        float bb = base1[j], uu = w1u[j], vv = w1v[j];
        #pragma unroll
        for (int p = 0; p < 32; ++p)
            h1[p][j] = fmaxf(bb + a0s[p] * uu + a1s[p] * vv, 0.f);
    }
    __syncthreads();

    const int pg = tid >> 7;
    const int kl = tid & 127;
    const float* W2h = W2 + (size_t)h * HID * HID + kl;

    float acc[16][4];
    #pragma unroll
    for (int p = 0; p < 16; ++p)
        #pragma unroll
        for (int dk = 0; dk < 4; ++dk) acc[p][dk] = 0.f;

    for (int j0 = 0; j0 < HID; j0 += 4) {
        float w[4][4];
        #pragma unroll
        for (int dj = 0; dj < 4; ++dj)
            #pragma unroll
            for (int dk = 0; dk < 4; ++dk)
                w[dj][dk] = W2h[(size_t)(j0 + dj) * HID + dk * 128];
        #pragma unroll
        for (int p = 0; p < 16; ++p) {
            const float4 hv = *(const float4*)&h1[pg * 16 + p][j0];
            #pragma unroll
            for (int dk = 0; dk < 4; ++dk)
                acc[p][dk] += hv.x * w[0][dk] + hv.y * w[1][dk]
                            + hv.z * w[2][dk] + hv.w * w[3][dk];
        }
    }

    float b2v[4], w3v[4];
    #pragma unroll
    for (int dk = 0; dk < 4; ++dk) {
        b2v[dk] = b2[h * HID + kl + dk * 128];
        w3v[dk] = W3[h * HID + kl + dk * 128];
    }
    const int wid  = tid >> 6;
    const int lane = tid & 63;
    const int wig  = wid & 1;
    #pragma unroll
    for (int p = 0; p < 16; ++p) {
        float v = 0.f;
        #pragma unroll
        for (int dk = 0; dk < 4; ++dk)
            v += fmaxf(acc[p][dk] + b2v[dk], 0.f) * w3v[dk];
        #pragma unroll
        for (int off = 32; off; off >>= 1) v += __shfl_down(v, off);
        if (lane == 0) red[pg][p][wig] = v;
    }
    __syncthreads();
    if (tid < 32) {
        int pp = tid & 15, g = tid >> 4;
        ws[WS_Q + (size_t)h * POP + p0 + g * 16 + pp] =
            red[g][pp][0] + red[g][pp][1];
        ws[WS_Q + (size_t)(HEADS + h) * POP + p0 + g * 16 + pp] = 0.f;
    }
}

// ---------------------------------------------------------------------------
// Kernel 3 (1024 threads): scores from q partials (+b3), exact top-819
// radix select, elite mean/std (ddof=1, double accum), best_a update.
// ---------------------------------------------------------------------------
__global__ __launch_bounds__(1024) void k_select(const float* __restrict__ noise,
                                                 const float* __restrict__ b3,
                                                 float* __restrict__ ws,
                                                 float* __restrict__ out, int t)
{
    __shared__ float    sc[POP];        // 16 KB
    __shared__ unsigned uk[POP];        // 16 KB
    __shared__ unsigned hist[256];
    __shared__ int      scan2[1024];
    __shared__ float    rf[1024];
    __shared__ int      ri_[1024];
    __shared__ double   rd[1024];
    __shared__ unsigned s_prefix;
    __shared__ int      s_r;

    const int tid = threadIdx.x;
    const float* q = ws + WS_Q;
    float* st = ws + WS_STATE;
    const float mu0 = st[0], mu1 = st[1], sd0 = st[2], sd1 = st[3];

    // scores = mean_h min(q1,q2); q[h] = part0 + part1 + b3[h]
    {
        const int p = tid * 4;
        f32x4 s = (f32x4){0.f, 0.f, 0.f, 0.f};
        #pragma unroll
        for (int hh = 0; hh < NH; ++hh) {
            f32x4 qa0 = *(const f32x4*)&q[(size_t)hh * POP + p];
            f32x4 qa1 = *(const f32x4*)&q[(size_t)(HEADS + hh) * POP + p];
            f32x4 qb0 = *(const f32x4*)&q[(size_t)(NH + hh) * POP + p];
            f32x4 qb1 = *(const f32x4*)&q[(size_t)(HEADS + NH + hh) * POP + p];
            float ba = b3[hh], bb = b3[NH + hh];
            #pragma unroll
            for (int i = 0; i < 4; ++i)
                s[i] += fminf(qa0[i] + qa1[i] + ba, qb0[i] + qb1[i] + bb);
        }
        #pragma unroll
        for (int i = 0; i < 4; ++i) {
            float v = s[i] * 0.2f;
            sc[p + i] = v;
            unsigned b = __float_as_uint(v);
            uk[p + i] = (b & 0x80000000u) ? ~b : (b | 0x80000000u);
        }
    }
    __syncthreads();

    // max + argmax (lowest index on ties); threads own disjoint ascending
    // index ranges so strict '>' keeps the lowest index within a thread.
    float mv = -3.402823466e38f; int mi = 0;
    #pragma unroll
    for (int k = 0; k < 4; ++k) {
        const int p = tid * 4 + k;
        float v = sc[p];
        if (v > mv) { mv = v; mi = p; }
    }
    rf[tid] = mv; ri_[tid] = mi;
    __syncthreads();
    for (int off = 512; off; off >>= 1) {
        if (tid < off) {
            float ov = rf[tid + off]; int oi = ri_[tid + off];
            if (ov > rf[tid] || (ov == rf[tid] && oi < ri_[tid])) {
                rf[tid] = ov; ri_[tid] = oi;
            }
        }
        __syncthreads();
    }
    const float maxsc = rf[0];
    const int argmax = ri_[0];
    __syncthreads();

    // radix select with parallel suffix-scan digit pick
    unsigned prefix = 0; int r = ELITE;
    for (int shift = 24; shift >= 0; shift -= 8) {
        if (tid < 256) hist[tid] = 0;
        __syncthreads();
        const unsigned himask = (shift < 24) ? (0xFFFFFFFFu << (shift + 8)) : 0u;
        for (int p = tid; p < POP; p += 1024) {
            unsigned key = uk[p];
            if ((key & himask) == prefix)
                atomicAdd(&hist[(key >> shift) & 255u], 1u);
        }
        __syncthreads();
        scan2[tid] = (tid < 256) ? (int)hist[tid] : 0;
        __syncthreads();
        for (int off = 1; off < 256; off <<= 1) {
            int v = (tid < 256 && tid + off < 256) ? scan2[tid + off] : 0;
            __syncthreads();
            if (tid < 256) scan2[tid] += v;
            __syncthreads();
        }
        if (tid < 256) {
            int above = (tid < 255) ? scan2[tid + 1] : 0;
            if (scan2[tid] >= r && above < r) {
                s_prefix = prefix | ((unsigned)tid << shift);
                s_r = r - above;
            }
        }
        __syncthreads();
        prefix = s_prefix; r = s_r;
        __syncthreads();
    }
    const unsigned uT = prefix;
    const int take = r;

    // tie ranks (index order) via prefix scan over contiguous 4-chunks
    int tieloc = 0;
    {
        const int base = tid * 4;
        #pragma unroll
        for (int k = 0; k < 4; ++k) if (uk[base + k] == uT) tieloc++;
    }
    scan2[tid] = tieloc;
    __syncthreads();
    for (int off = 1; off < 1024; off <<= 1) {
        int v = (tid >= off) ? scan2[tid - off] : 0;
        __syncthreads();
        scan2[tid] += v;
        __syncthreads();
    }
    const int tieExcl = scan2[tid] - tieloc;

    double s0 = 0, s1 = 0, ss0 = 0, ss1 = 0;
    {
        const int base = tid * 4;
        int trank = tieExcl;
        #pragma unroll
        for (int k = 0; k < 4; ++k) {
            const int p = base + k;
            const unsigned key = uk[p];
            bool inc = false;
            if (key > uT) inc = true;
            else if (key == uT) { if (trank < take) inc = true; trank++; }
            if (inc) {
                float e0 = noise[((size_t)t * POP + p) * 2 + 0];
                float e1 = noise[((size_t)t * POP + p) * 2 + 1];
                float a0 = fminf(fmaxf(mu0 + sd0 * e0, -1.f), 1.f);
                float a1 = fminf(fmaxf(mu1 + sd1 * e1, -1.f), 1.f);
                s0 += a0; s1 += a1;
                ss0 += (double)a0 * a0; ss1 += (double)a1 * a1;
            }
        }
    }
    double S0, S1, SS0, SS1;
    rd[tid] = s0;  __syncthreads();
    for (int off = 512; off; off >>= 1) { if (tid < off) rd[tid] += rd[tid + off]; __syncthreads(); }
    S0 = rd[0]; __syncthreads();
    rd[tid] = s1;  __syncthreads();
    for (int off = 512; off; off >>= 1) { if (tid < off) rd[tid] += rd[tid + off]; __syncthreads(); }
    S1 = rd[0]; __syncthreads();
    rd[tid] = ss0; __syncthreads();
    for (int off = 512; off; off >>= 1) { if (tid < off) rd[tid] += rd[tid + off]; __syncthreads(); }
    SS0 = rd[0]; __syncthreads();
    rd[tid] = ss1; __syncthreads();
    for (int off = 512; off; off >>= 1) { if (tid < off) rd[tid] += rd[tid + off]; __syncthreads(); }
    SS1 = rd[0]; __syncthreads();

    if (tid == 0) {
        const double n = (double)ELITE;
        double m0 = S0 / n, m1 = S1 / n;
        double v0 = (SS0 - S0 * S0 / n) / (n - 1.0);
        double v1 = (SS1 - S1 * S1 / n) / (n - 1.0);
        float nsd0 = fmaxf((float)sqrt(fmax(v0, 0.0)), MIN_STDF);
        float nsd1 = fmaxf((float)sqrt(fmax(v1, 0.0)), MIN_STDF);
        float e0 = noise[((size_t)t * POP + argmax) * 2 + 0];
        float e1 = noise[((size_t)t * POP + argmax) * 2 + 1];
        float a0 = fminf(fmaxf(mu0 + sd0 * e0, -1.f), 1.f);
        float a1 = fminf(fmaxf(mu1 + sd1 * e1, -1.f), 1.f);
        if (maxsc > st[6]) { st[4] = a0; st[5] = a1; st[6] = maxsc; }
        st[0] = (float)m0; st[1] = (float)m1; st[2] = nsd0; st[3] = nsd1;
        if (t == ITERS - 1) { out[0] = st[4]; out[1] = st[5]; }
    }
}

// ---------------------------------------------------------------------------
extern "C" void kernel_launch(void* const* d_in, const int* in_sizes, int n_in,
                              void* d_out, int out_size, void* d_ws, size_t ws_size,
                              hipStream_t stream)
{
    const float* state = (const float*)d_in[0];
    const float* noise = (const float*)d_in[1];
    const float* W1    = (const float*)d_in[2];
    const float* b1    = (const float*)d_in[3];
    const float* W2    = (const float*)d_in[4];
    const float* b2    = (const float*)d_in[5];
    const float* W3    = (const float*)d_in[6];
    const float* b3    = (const float*)d_in[7];
    float* out = (float*)d_out;
    float* ws  = (float*)d_ws;

    const bool fast = ws_size >= WS_NEED_BYTES;

    k_base<<<dim3(2, HEADS), 256, 0, stream>>>(state, W1, b1, ws);
    if (fast) {
        unsigned short* W2S = (unsigned short*)((char*)d_ws + WS_W2S_BYTE);
        k_split<<<dim3(16, 2, HEADS), 256, 0, stream>>>(W2, W2S);
        for (int t = 0; t < ITERS; ++t) {
            k_score_mfma10<<<dim3(1280), 512, 0, stream>>>(
                noise, W1, W2S, b2, W3, ws, t);
            k_select<<<1, 1024, 0, stream>>>(noise, b3, ws, out, t);
        }
    } else {
        for (int t = 0; t < ITERS; ++t) {
            k_score<<<dim3(POP / 32, HEADS), 256, 0, stream>>>(noise, W1, W2, b2, W3, ws, t);
            k_select<<<1, 1024, 0, stream>>>(noise, b3, ws, out, t);
        }
    }
}